// Round 7
// baseline (155.864 us; speedup 1.0000x reference)
//
#include <hip/hip_runtime.h>
#include <hip/hip_bf16.h>
#include <hip/hip_cooperative_groups.h>

namespace cg = cooperative_groups;

// Problem constants
#define NB    16
#define NC    1024
#define NF    4096
#define MROWS 65536      // NB*NF
#define CIN   256
#define CSK   128
#define DIN   384        // CIN + CSK
#define CHID  256
#define BN_EPS 1e-5f

typedef __attribute__((ext_vector_type(8))) short bf16x8;
typedef __attribute__((ext_vector_type(4))) float f32x4;

__device__ __forceinline__ unsigned short f2bfu(float f) {
  __hip_bfloat16 h = __float2bfloat16(f);
  return __builtin_bit_cast(unsigned short, h);
}
__device__ __forceinline__ float bfu2f(unsigned short u) {
  unsigned int w = ((unsigned int)u) << 16;
  return __builtin_bit_cast(float, w);
}

__device__ __forceinline__ void load_lds16(const void* g, void* lds) {
  __builtin_amdgcn_global_load_lds(
      (const __attribute__((address_space(1))) unsigned int*)g,
      (__attribute__((address_space(3))) unsigned int*)lds, 16, 0, 0);
}

// sorted top-3 insert, strict-< (lower index wins ties; inserted element must
// have index larger than all currently held — true for ascending scans/merges)
__device__ __forceinline__ void ins3(float d2, int j, float& b0, float& b1,
                                     float& b2v, int& i0, int& i1, int& i2) {
  const bool c0 = d2 < b0, c1 = d2 < b1, c2 = d2 < b2v;
  const float nb1 = __builtin_amdgcn_fmed3f(d2, b0, b1);
  const float nb2 = __builtin_amdgcn_fmed3f(d2, b1, b2v);
  i2  = c1 ? i1 : (c2 ? j : i2);
  i1  = c0 ? i0 : (c1 ? j : i1);
  i0  = c0 ? j : i0;
  b2v = nb2;
  b1  = nb1;
  b0  = fminf(d2, b0);
}

// sorted top-3 insert with full (d, idx) lexicographic tiebreak — order-
// independent, used for cross-lane merges. Distance updates via med3 are
// value-correct even on ties; only index selection needs the tiebreak.
__device__ __forceinline__ void ins3tb(float d, int j, float& b0, float& b1,
                                       float& b2v, int& i0, int& i1, int& i2) {
  const bool c0 = (d < b0) || (d == b0 && j < i0);
  const bool c1 = (d < b1) || (d == b1 && j < i1);
  const bool c2 = (d < b2v) || (d == b2v && j < i2);
  const float nb1 = __builtin_amdgcn_fmed3f(d, b0, b1);
  const float nb2 = __builtin_amdgcn_fmed3f(d, b1, b2v);
  i2  = c1 ? i1 : (c2 ? j : i2);
  i1  = c0 ? i0 : (c1 ? j : i1);
  i0  = c0 ? j : i0;
  b2v = nb2;
  b1  = nb1;
  b0  = fminf(d, b0);
}

// ---------------------------------------------------------------------------
// K1: kNN interpolate + concat -> h0 (MROWS x 384, bf16)
// Blocks [0,2048): 256 thr / 4 waves; wave owns 8 points (8 lanes per point);
// each lane scans a 128-candidate strip as TWO independent 64-cand chains
// (ILP), merges in-register, then 3-round shfl_xor merge across the 8-lane
// group with (d,idx) tiebreak == exact lax.top_k semantics.
// Candidate tile interleaved cpos[t*8+ll] -> 8 distinct bank-quads, no LDS
// conflicts. Blocks [2048,2432): W1 transpose prep + stats zeroing.
// ---------------------------------------------------------------------------
__global__ __launch_bounds__(256) void knn_interp_kernel(
    const float* __restrict__ x,        // (NB*NC, 256)
    const float* __restrict__ pos,      // (NB*NC, 3)
    const float* __restrict__ x_skip,   // (NB*NF, 128)
    const float* __restrict__ pos_skip, // (NB*NF, 3)
    __hip_bfloat16* __restrict__ h0,    // (MROWS, 384)
    const float* __restrict__ W1,
    __hip_bfloat16* __restrict__ W1t,
    float* __restrict__ stats)
{
  const int tid = threadIdx.x, wid = tid >> 6, lane = tid & 63;

  if (blockIdx.x >= 2048) {            // prep-W1 role (block-uniform branch)
    const int c = blockIdx.x - 2048;   // 0..383
    if (c == 0) {
      for (int k = tid; k < 1024; k += 256) stats[k] = 0.f;
    }
    W1t[(size_t)tid * DIN + c] = __float2bfloat16(W1[(size_t)c * CHID + tid]);
    return;
  }

  __shared__ float4 cposI[NC];         // interleaved: cand (strip ll, t) at t*8+ll
  __shared__ float  fw[32][3];
  __shared__ int    fi[32][3];

  const int f0 = blockIdx.x * 32;      // 32 fine points per block
  const int b  = f0 >> 12;             // batch (4096 fine pts / batch)

  const float* pb = pos + (size_t)b * NC * 3;
  for (int j = tid; j < NC; j += 256) {
    cposI[((j & 127) << 3) | (j >> 7)] =
        make_float4(pb[3 * j], pb[3 * j + 1], pb[3 * j + 2], 0.f);
  }
  __syncthreads();

  const int ll = lane & 7;             // strip index within 8-lane group
  const int pl = wid * 8 + (lane >> 3);// local point 0..31
  const int f  = f0 + pl;
  const float fx = pos_skip[(size_t)f * 3];
  const float fy = pos_skip[(size_t)f * 3 + 1];
  const float fz = pos_skip[(size_t)f * 3 + 2];
  const int jb = ll * 128;             // strip candidate base

  // two independent chains: A = [jb, jb+64), B = [jb+64, jb+128)
  float a0 = 3.4e38f, a1 = 3.4e38f, a2 = 3.4e38f;
  float c0 = 3.4e38f, c1 = 3.4e38f, c2 = 3.4e38f;
  int ia0 = 0, ia1 = 0, ia2 = 0, ic0 = 0, ic1 = 0, ic2 = 0;
#pragma unroll 4
  for (int t = 0; t < 64; ++t) {
    const float4 pA = cposI[t * 8 + ll];
    const float4 pB = cposI[(t + 64) * 8 + ll];
    const float dxA = __fsub_rn(fx, pA.x), dyA = __fsub_rn(fy, pA.y),
                dzA = __fsub_rn(fz, pA.z);
    const float dxB = __fsub_rn(fx, pB.x), dyB = __fsub_rn(fy, pB.y),
                dzB = __fsub_rn(fz, pB.z);
    const float d2A = __fadd_rn(
        __fadd_rn(__fmul_rn(dxA, dxA), __fmul_rn(dyA, dyA)),
        __fmul_rn(dzA, dzA));
    const float d2B = __fadd_rn(
        __fadd_rn(__fmul_rn(dxB, dxB), __fmul_rn(dyB, dyB)),
        __fmul_rn(dzB, dzB));
    ins3(d2A, jb + t,      a0, a1, a2, ia0, ia1, ia2);
    ins3(d2B, jb + 64 + t, c0, c1, c2, ic0, ic1, ic2);
  }
  // merge chain B into A (all B indices > all A indices -> strict-<)
  ins3(c0, ic0, a0, a1, a2, ia0, ia1, ia2);
  ins3(c1, ic1, a0, a1, a2, ia0, ia1, ia2);
  ins3(c2, ic2, a0, a1, a2, ia0, ia1, ia2);

  // cross-lane merge within the 8-lane group (tiebreak compare)
#pragma unroll
  for (int mm = 1; mm <= 4; mm <<= 1) {
    const float o0 = __shfl_xor(a0, mm);
    const float o1 = __shfl_xor(a1, mm);
    const float o2 = __shfl_xor(a2, mm);
    const int oj0 = __shfl_xor(ia0, mm);
    const int oj1 = __shfl_xor(ia1, mm);
    const int oj2 = __shfl_xor(ia2, mm);
    ins3tb(o0, oj0, a0, a1, a2, ia0, ia1, ia2);
    ins3tb(o1, oj1, a0, a1, a2, ia0, ia1, ia2);
    ins3tb(o2, oj2, a0, a1, a2, ia0, ia1, ia2);
  }

  if (ll == 0) {
    float w0 = 1.f / fmaxf(a0, 1e-16f);
    float w1 = 1.f / fmaxf(a1, 1e-16f);
    float w2 = 1.f / fmaxf(a2, 1e-16f);
    const float inv = 1.f / (w0 + w1 + w2);
    fw[pl][0] = w0 * inv; fw[pl][1] = w1 * inv; fw[pl][2] = w2 * inv;
    fi[pl][0] = ia0; fi[pl][1] = ia1; fi[pl][2] = ia2;
  }
  __syncthreads();

  // gather: wave w handles points p = w*8 .. w*8+7 (64-lane coalesced rows)
  for (int pp = 0; pp < 8; ++pp) {
    const int p = wid * 8 + pp;
    const float w0 = fw[p][0], w1 = fw[p][1], w2 = fw[p][2];
    const int j0 = fi[p][0], j1 = fi[p][1], j2 = fi[p][2];
    const float4* r0 = (const float4*)(x + (size_t)(b * NC + j0) * CIN);
    const float4* r1 = (const float4*)(x + (size_t)(b * NC + j1) * CIN);
    const float4* r2 = (const float4*)(x + (size_t)(b * NC + j2) * CIN);
    const float4 a0v = r0[lane], a1v = r1[lane], a2v = r2[lane];
    float4 v;
    v.x = w0 * a0v.x + w1 * a1v.x + w2 * a2v.x;
    v.y = w0 * a0v.y + w1 * a1v.y + w2 * a2v.y;
    v.z = w0 * a0v.z + w1 * a1v.z + w2 * a2v.z;
    v.w = w0 * a0v.w + w1 * a1v.w + w2 * a2v.w;
    __hip_bfloat16* orow = h0 + (size_t)(f0 + p) * DIN;
    ushort4 o;
    o.x = f2bfu(v.x); o.y = f2bfu(v.y); o.z = f2bfu(v.z); o.w = f2bfu(v.w);
    ((ushort4*)orow)[lane] = o;
    const float2 s = ((const float2*)(x_skip + (size_t)(f0 + p) * CSK))[lane];
    const unsigned int packed =
        ((unsigned int)f2bfu(s.y) << 16) | (unsigned int)f2bfu(s.x);
    ((unsigned int*)(orow + CIN))[lane] = packed;
  }
}

// ---------------------------------------------------------------------------
// Fused BN1-finalize + W2 fold + b2 fold.
// ---------------------------------------------------------------------------
__global__ __launch_bounds__(256) void prep_w2b2_kernel(
    const float* __restrict__ W2, const float* __restrict__ stats,
    const float* __restrict__ g1, const float* __restrict__ be1,
    const float* __restrict__ b2, __hip_bfloat16* __restrict__ W2t,
    float* __restrict__ b2p) {
  const int n = blockIdx.x, c = threadIdx.x;
  const int wid = c >> 6, lane = c & 63;
  const float m = stats[c] * (1.f / MROWS);
  const float var = stats[256 + c] * (1.f / MROWS) - m * m;
  const float sc = g1[c] * rsqrtf(var + BN_EPS);
  const float sh = be1[c] - m * sc;
  const float w = W2[(size_t)c * CHID + n];
  W2t[(size_t)n * CHID + c] = __float2bfloat16(sc * w);
  float p = sh * w;
#pragma unroll
  for (int off = 32; off > 0; off >>= 1) p += __shfl_down(p, off);
  __shared__ float red4[4];
  if (lane == 0) red4[wid] = p;
  __syncthreads();
  if (c == 0) b2p[n] = red4[0] + red4[1] + red4[2] + red4[3] + b2[n];
}

// ---------------------------------------------------------------------------
// GEMM1: z1 = relu(h0 @ W1t^T + b1), bf16 out + fused BN1 stats.
// 128x256 tile, BK=32, 8 waves, 2-phase prefetch dbuf (r6, proven).
// ---------------------------------------------------------------------------
template<int KD>
__global__ __launch_bounds__(512) void gemm_bias_relu(
    const __hip_bfloat16* __restrict__ A,   // M x KD
    const __hip_bfloat16* __restrict__ Bt,  // 256 x KD
    const float* __restrict__ bias,         // 256
    __hip_bfloat16* __restrict__ out,       // M x 256 (bf16)
    float* __restrict__ gsum,               // 256
    float* __restrict__ gsq)                // 256
{
  __shared__ __hip_bfloat16 As[2 * 128 * 32];   // 16 KB
  __shared__ __hip_bfloat16 Bs[2 * 256 * 32];   // 32 KB
  __shared__ float ssum[256], ssq[256];
  const int tid = threadIdx.x;
  const int wid = tid >> 6, lane = tid & 63;
  const int bm = blockIdx.x;
  const int wr = wid >> 2, wc = wid & 3;
  const int la = lane & 15, lk = lane >> 4;

  if (tid < 256) { ssum[tid] = 0.f; ssq[tid] = 0.f; }

  f32x4 acc[4][4] = {};

  const int rA = tid >> 2;
  const int c8 = (tid & 3) * 8;
  const __hip_bfloat16* gA  = A  + (size_t)(bm * 128 + rA) * KD + c8;
  const __hip_bfloat16* gB0 = Bt + (size_t)rA * KD + c8;
  const __hip_bfloat16* gB1 = Bt + (size_t)(128 + rA) * KD + c8;
  char* ldsA  = (char*)As + wid * 1024;
  char* ldsB0 = (char*)Bs + wid * 1024;

  load_lds16(gA,  ldsA);
  load_lds16(gB0, ldsB0);
  load_lds16(gB1, ldsB0 + 8192);
  __syncthreads();

  const int nIter = KD / 32;
  for (int it = 0; it < nIter; ++it) {
    const int cur = it & 1, nxt = cur ^ 1;
    if (it + 1 < nIter) {
      const int k1 = (it + 1) * 32;
      load_lds16(gA  + k1, ldsA  + nxt * 8192);
      load_lds16(gB0 + k1, ldsB0 + nxt * 16384);
      load_lds16(gB1 + k1, ldsB0 + nxt * 16384 + 8192);
    }
    const __hip_bfloat16* Acur = As + cur * 4096;
    const __hip_bfloat16* Bcur = Bs + cur * 8192;
    bf16x8 af[4], bfr[4];
#pragma unroll
    for (int m = 0; m < 4; ++m)
      af[m] = *(const bf16x8*)(Acur + (wr * 64 + m * 16 + la) * 32 + lk * 8);
#pragma unroll
    for (int n = 0; n < 4; ++n)
      bfr[n] = *(const bf16x8*)(Bcur + (wc * 64 + n * 16 + la) * 32 + lk * 8);
#pragma unroll
    for (int m = 0; m < 4; ++m)
#pragma unroll
      for (int n = 0; n < 4; ++n)
        acc[m][n] = __builtin_amdgcn_mfma_f32_16x16x32_bf16(
            af[m], bfr[n], acc[m][n], 0, 0, 0);
    __syncthreads();
  }

  const int rowBase = bm * 128 + wr * 64 + lk * 4;
#pragma unroll
  for (int n = 0; n < 4; ++n) {
    const int col = wc * 64 + n * 16 + la;
    const float bs = bias[col];
    float ls = 0.f, ls2 = 0.f;
#pragma unroll
    for (int m = 0; m < 4; ++m) {
      const int row = rowBase + m * 16;
#pragma unroll
      for (int j = 0; j < 4; ++j) {
        float v = acc[m][n][j] + bs;
        v = fmaxf(v, 0.f);
        ls += v; ls2 += v * v;
        out[(size_t)(row + j) * 256 + col] = __float2bfloat16(v);
      }
    }
    atomicAdd(&ssum[col], ls);
    atomicAdd(&ssq[col], ls2);
  }
  __syncthreads();
  if (tid < 256) {
    atomicAdd(&gsum[tid], ssum[tid]);
    atomicAdd(&gsq[tid], ssq[tid]);
  }
}

// ---------------------------------------------------------------------------
// One 128-row GEMM tile into acc (2-phase prefetch), used by the fused kernel.
// ---------------------------------------------------------------------------
__device__ __forceinline__ void gemm_tile_256(
    const __hip_bfloat16* __restrict__ A, const __hip_bfloat16* __restrict__ Bt,
    int bm, __hip_bfloat16* As, __hip_bfloat16* Bs,
    int tid, int wid, int wr, int wc, int la, int lk, f32x4 (&acc)[4][4]) {
  const int rA = tid >> 2;
  const int c8 = (tid & 3) * 8;
  const __hip_bfloat16* gA  = A  + (size_t)(bm * 128 + rA) * CHID + c8;
  const __hip_bfloat16* gB0 = Bt + (size_t)rA * CHID + c8;
  const __hip_bfloat16* gB1 = Bt + (size_t)(128 + rA) * CHID + c8;
  char* ldsA  = (char*)As + wid * 1024;
  char* ldsB0 = (char*)Bs + wid * 1024;

  load_lds16(gA,  ldsA);
  load_lds16(gB0, ldsB0);
  load_lds16(gB1, ldsB0 + 8192);
  __syncthreads();

  for (int it = 0; it < CHID / 32; ++it) {
    const int cur = it & 1, nxt = cur ^ 1;
    if (it + 1 < CHID / 32) {
      const int k1 = (it + 1) * 32;
      load_lds16(gA  + k1, ldsA  + nxt * 8192);
      load_lds16(gB0 + k1, ldsB0 + nxt * 16384);
      load_lds16(gB1 + k1, ldsB0 + nxt * 16384 + 8192);
    }
    const __hip_bfloat16* Acur = As + cur * 4096;
    const __hip_bfloat16* Bcur = Bs + cur * 8192;
    bf16x8 af[4], bfr[4];
#pragma unroll
    for (int m = 0; m < 4; ++m)
      af[m] = *(const bf16x8*)(Acur + (wr * 64 + m * 16 + la) * 32 + lk * 8);
#pragma unroll
    for (int n = 0; n < 4; ++n)
      bfr[n] = *(const bf16x8*)(Bcur + (wc * 64 + n * 16 + la) * 32 + lk * 8);
#pragma unroll
    for (int m = 0; m < 4; ++m)
#pragma unroll
      for (int n = 0; n < 4; ++n)
        acc[m][n] = __builtin_amdgcn_mfma_f32_16x16x32_bf16(
            af[m], bfr[n], acc[m][n], 0, 0, 0);
    __syncthreads();
  }
}

// ---------------------------------------------------------------------------
// GEMM2 + BN2 fully fused (cooperative): 256 blocks, 2 tiles each, relu'd
// accumulators stay in registers across grid.sync(); f32 out written once.
// No z2 intermediate at all.
// ---------------------------------------------------------------------------
__global__ __launch_bounds__(512, 2) void gemm2_bn_fused(
    const __hip_bfloat16* __restrict__ A,   // z1: M x 256
    const __hip_bfloat16* __restrict__ Bt,  // W2t: 256 x 256
    const float* __restrict__ bias,         // b2p
    float* __restrict__ gsum, float* __restrict__ gsq,
    const float* __restrict__ g2, const float* __restrict__ be2,
    float* __restrict__ out)                // M x 256 f32
{
  __shared__ __hip_bfloat16 As[2 * 128 * 32];
  __shared__ __hip_bfloat16 Bs[2 * 256 * 32];
  __shared__ float ssum[256], ssq[256];
  const int tid = threadIdx.x;
  const int wid = tid >> 6, lane = tid & 63;
  const int wr = wid >> 2, wc = wid & 3;
  const int la = lane & 15, lk = lane >> 4;
  const int bmA = blockIdx.x * 2, bmB = bmA + 1;

  if (tid < 256) { ssum[tid] = 0.f; ssq[tid] = 0.f; }

  f32x4 accA[4][4] = {};
  f32x4 accB[4][4] = {};
  gemm_tile_256(A, Bt, bmA, As, Bs, tid, wid, wr, wc, la, lk, accA);
  gemm_tile_256(A, Bt, bmB, As, Bs, tid, wid, wr, wc, la, lk, accB);

  // relu in place + column stats for both tiles
#pragma unroll
  for (int n = 0; n < 4; ++n) {
    const int col = wc * 64 + n * 16 + la;
    const float bs = bias[col];
    float ls = 0.f, ls2 = 0.f;
#pragma unroll
    for (int m = 0; m < 4; ++m)
#pragma unroll
      for (int j = 0; j < 4; ++j) {
        float vA = fmaxf(accA[m][n][j] + bs, 0.f);
        float vB = fmaxf(accB[m][n][j] + bs, 0.f);
        accA[m][n][j] = vA; accB[m][n][j] = vB;
        ls += vA + vB; ls2 += vA * vA + vB * vB;
      }
    atomicAdd(&ssum[col], ls);
    atomicAdd(&ssq[col], ls2);
  }
  __syncthreads();
  if (tid < 256) {
    atomicAdd(&gsum[tid], ssum[tid]);
    atomicAdd(&gsq[tid], ssq[tid]);
  }

  cg::this_grid().sync();

  // BN2 finalize per owned column + apply + f32 store (both tiles)
#pragma unroll
  for (int n = 0; n < 4; ++n) {
    const int col = wc * 64 + n * 16 + la;
    const float m_ = gsum[col] * (1.f / MROWS);
    const float var = gsq[col] * (1.f / MROWS) - m_ * m_;
    const float sc = g2[col] * rsqrtf(var + BN_EPS);
    const float sh = be2[col] - m_ * sc;
    const int rbA = bmA * 128 + wr * 64 + lk * 4;
    const int rbB = bmB * 128 + wr * 64 + lk * 4;
#pragma unroll
    for (int m = 0; m < 4; ++m) {
#pragma unroll
      for (int j = 0; j < 4; ++j) {
        out[(size_t)(rbA + m * 16 + j) * 256 + col] = accA[m][n][j] * sc + sh;
        out[(size_t)(rbB + m * 16 + j) * 256 + col] = accB[m][n][j] * sc + sh;
      }
    }
  }
}

// ---------------------------------------------------------------------------
// Fallback path kernels (used only if cooperative launch is rejected)
// ---------------------------------------------------------------------------
__global__ __launch_bounds__(256) void bn_apply_kernel(
    const __hip_bfloat16* __restrict__ Z, const float* __restrict__ stats,
    const float* __restrict__ g2, const float* __restrict__ be2,
    float* __restrict__ out) {
  __shared__ float ssc[256], ssh[256];
  const int t = threadIdx.x;
  {
    const float m = stats[t] * (1.f / MROWS);
    const float var = stats[256 + t] * (1.f / MROWS) - m * m;
    const float sc = g2[t] * rsqrtf(var + BN_EPS);
    ssc[t] = sc;
    ssh[t] = be2[t] - m * sc;
  }
  __syncthreads();
  const size_t i8 = (size_t)blockIdx.x * 256 + t;
  const uint4 raw = ((const uint4*)Z)[i8];
  const int c0 = (int)((i8 * 8) & 255);
  const float4 scA = *(const float4*)(ssc + c0);
  const float4 scB = *(const float4*)(ssc + c0 + 4);
  const float4 shA = *(const float4*)(ssh + c0);
  const float4 shB = *(const float4*)(ssh + c0 + 4);
  float4 oa, ob;
  oa.x = bfu2f((unsigned short)(raw.x & 0xffff)) * scA.x + shA.x;
  oa.y = bfu2f((unsigned short)(raw.x >> 16))    * scA.y + shA.y;
  oa.z = bfu2f((unsigned short)(raw.y & 0xffff)) * scA.z + shA.z;
  oa.w = bfu2f((unsigned short)(raw.y >> 16))    * scA.w + shA.w;
  ob.x = bfu2f((unsigned short)(raw.z & 0xffff)) * scB.x + shB.x;
  ob.y = bfu2f((unsigned short)(raw.z >> 16))    * scB.y + shB.y;
  ob.z = bfu2f((unsigned short)(raw.w & 0xffff)) * scB.z + shB.z;
  ob.w = bfu2f((unsigned short)(raw.w >> 16))    * scB.w + shB.w;
  ((float4*)(out))[i8 * 2]     = oa;
  ((float4*)(out))[i8 * 2 + 1] = ob;
}

// ---------------------------------------------------------------------------
extern "C" void kernel_launch(void* const* d_in, const int* in_sizes, int n_in,
                              void* d_out, int out_size, void* d_ws,
                              size_t ws_size, hipStream_t stream) {
  (void)in_sizes; (void)n_in; (void)out_size; (void)ws_size;
  const float* x        = (const float*)d_in[0];
  const float* pos      = (const float*)d_in[1];
  const float* x_skip   = (const float*)d_in[3];
  const float* pos_skip = (const float*)d_in[4];
  const float* W1  = (const float*)d_in[6];
  const float* b1  = (const float*)d_in[7];
  const float* g1  = (const float*)d_in[8];
  const float* be1 = (const float*)d_in[9];
  const float* W2  = (const float*)d_in[10];
  const float* b2  = (const float*)d_in[11];
  const float* g2  = (const float*)d_in[12];
  const float* be2 = (const float*)d_in[13];
  float* out = (float*)d_out;

  char* ws = (char*)d_ws;
  __hip_bfloat16* h0  = (__hip_bfloat16*)(ws);                    // 50331648
  __hip_bfloat16* z2  = (__hip_bfloat16*)(ws);                    // fallback only
  __hip_bfloat16* W1t = (__hip_bfloat16*)(ws + 50331648);         // 196608
  __hip_bfloat16* z1  = (__hip_bfloat16*)(ws + 50528256);         // 33554432
  __hip_bfloat16* W2t = (__hip_bfloat16*)(ws + 84082688);         // 131072
  float* b2p    = (float*)(ws + 84213760);                        // 1024
  float* stats  = (float*)(ws + 84214784);                        // 4096

  knn_interp_kernel<<<2432, 256, 0, stream>>>(x, pos, x_skip, pos_skip, h0,
                                              W1, W1t, stats);
  gemm_bias_relu<DIN><<<512, 512, 0, stream>>>(h0, W1t, b1, z1,
                                               stats, stats + 256);
  prep_w2b2_kernel<<<256, 256, 0, stream>>>(W2, stats, g1, be1, b2, W2t, b2p);

  {
    const __hip_bfloat16* a2 = z1;
    const __hip_bfloat16* bt2 = W2t;
    const float* bias2 = b2p;
    float* gsum2 = stats + 512;
    float* gsq2  = stats + 768;
    void* args[] = {(void*)&a2, (void*)&bt2, (void*)&bias2,
                    (void*)&gsum2, (void*)&gsq2,
                    (void*)&g2, (void*)&be2, (void*)&out};
    hipError_t e = hipLaunchCooperativeKernel((const void*)gemm2_bn_fused,
                                              dim3(256), dim3(512), args, 0,
                                              stream);
    if (e != hipSuccess) {
      (void)hipGetLastError();   // clear sticky error; deterministic fallback
      gemm_bias_relu<CHID><<<512, 512, 0, stream>>>(z1, W2t, b2p, z2,
                                                    stats + 512, stats + 768);
      bn_apply_kernel<<<8192, 256, 0, stream>>>(z2, stats + 512, g2, be2, out);
    }
  }
}

// Round 8
// 133.283 us; speedup vs baseline: 1.1694x; 1.1694x over previous
//
#include <hip/hip_runtime.h>
#include <hip/hip_bf16.h>

// Problem constants
#define NB    16
#define NC    1024
#define NF    4096
#define MROWS 65536      // NB*NF
#define CIN   256
#define CSK   128
#define DIN   384        // CIN + CSK
#define CHID  256
#define BN_EPS 1e-5f

typedef __attribute__((ext_vector_type(8))) short bf16x8;
typedef __attribute__((ext_vector_type(4))) float f32x4;

__device__ __forceinline__ unsigned short f2bfu(float f) {
  __hip_bfloat16 h = __float2bfloat16(f);
  return __builtin_bit_cast(unsigned short, h);
}
__device__ __forceinline__ float bfu2f(unsigned short u) {
  unsigned int w = ((unsigned int)u) << 16;
  return __builtin_bit_cast(float, w);
}
__device__ __forceinline__ unsigned int pack2(float lo, float hi) {
  return ((unsigned int)f2bfu(hi) << 16) | (unsigned int)f2bfu(lo);
}

__device__ __forceinline__ void load_lds16(const void* g, void* lds) {
  __builtin_amdgcn_global_load_lds(
      (const __attribute__((address_space(1))) unsigned int*)g,
      (__attribute__((address_space(3))) unsigned int*)lds, 16, 0, 0);
}

// sorted top-3 insert, strict-< (valid when inserted index > all held indices)
__device__ __forceinline__ void ins3(float d2, int j, float& b0, float& b1,
                                     float& b2v, int& i0, int& i1, int& i2) {
  const bool c0 = d2 < b0, c1 = d2 < b1, c2 = d2 < b2v;
  const float nb1 = __builtin_amdgcn_fmed3f(d2, b0, b1);
  const float nb2 = __builtin_amdgcn_fmed3f(d2, b1, b2v);
  i2  = c1 ? i1 : (c2 ? j : i2);
  i1  = c0 ? i0 : (c1 ? j : i1);
  i0  = c0 ? j : i0;
  b2v = nb2;
  b1  = nb1;
  b0  = fminf(d2, b0);
}

// sorted top-3 insert with (d, idx) lexicographic tiebreak — order-independent
__device__ __forceinline__ void ins3tb(float d, int j, float& b0, float& b1,
                                       float& b2v, int& i0, int& i1, int& i2) {
  const bool c0 = (d < b0) || (d == b0 && j < i0);
  const bool c1 = (d < b1) || (d == b1 && j < i1);
  const bool c2 = (d < b2v) || (d == b2v && j < i2);
  const float nb1 = __builtin_amdgcn_fmed3f(d, b0, b1);
  const float nb2 = __builtin_amdgcn_fmed3f(d, b1, b2v);
  i2  = c1 ? i1 : (c2 ? j : i2);
  i1  = c0 ? i0 : (c1 ? j : i1);
  i0  = c0 ? j : i0;
  b2v = nb2;
  b1  = nb1;
  b0  = fminf(d, b0);
}

// ---------------------------------------------------------------------------
// K1: kNN interpolate + concat -> h0 (MROWS x 384, bf16)
// Blocks [0,2048): 256 thr; 8 lanes per point; lane scans its 128-cand strip
// as two independent 64-chains (ILP), merges in-register, 3-round shfl_xor
// butterfly (lexicographic tiebreak == lax.top_k). After the symmetric merge
// ALL 8 lanes hold the point's top-3 -> direct per-group gather, no barrier.
// LDS slot swizzle (strip ^ (T&7)) breaks the 128B-stride write conflict.
// Blocks [2048,2432): W1 transpose prep + stats zeroing.
// ---------------------------------------------------------------------------
__global__ __launch_bounds__(256) void knn_interp_kernel(
    const float* __restrict__ x,        // (NB*NC, 256)
    const float* __restrict__ pos,      // (NB*NC, 3)
    const float* __restrict__ x_skip,   // (NB*NF, 128)
    const float* __restrict__ pos_skip, // (NB*NF, 3)
    __hip_bfloat16* __restrict__ h0,    // (MROWS, 384)
    const float* __restrict__ W1,
    __hip_bfloat16* __restrict__ W1t,
    float* __restrict__ stats)
{
  const int tid = threadIdx.x, lane = tid & 63, wid = tid >> 6;

  if (blockIdx.x >= 2048) {            // prep-W1 role (block-uniform branch)
    const int c = blockIdx.x - 2048;   // 0..383
    if (c == 0) {
      for (int k = tid; k < 1024; k += 256) stats[k] = 0.f;
    }
    W1t[(size_t)tid * DIN + c] = __float2bfloat16(W1[(size_t)c * CHID + tid]);
    return;
  }

  __shared__ float4 cposI[NC];         // swizzled slots, 16 KB

  const int f0 = blockIdx.x * 32;      // 32 fine points per block
  const int b  = f0 >> 12;             // batch (4096 fine pts / batch)

  // stage: candidate j -> slot ((j&127)<<3) | ((j>>7) ^ (j&7))
  const float* pb = pos + (size_t)b * NC * 3;
  for (int j = tid; j < NC; j += 256) {
    const int slot = ((j & 127) << 3) | ((j >> 7) ^ (j & 7));
    cposI[slot] = make_float4(pb[3 * j], pb[3 * j + 1], pb[3 * j + 2], 0.f);
  }
  __syncthreads();

  const int ll = lane & 7;             // strip index within 8-lane group
  const int pl = wid * 8 + (lane >> 3);// local point 0..31
  const int f  = f0 + pl;
  const float fx = pos_skip[(size_t)f * 3];
  const float fy = pos_skip[(size_t)f * 3 + 1];
  const float fz = pos_skip[(size_t)f * 3 + 2];
  const int jb = ll * 128;             // strip candidate base

  // two independent chains: A = [jb, jb+64), B = [jb+64, jb+128)
  float a0 = 3.4e38f, a1 = 3.4e38f, a2 = 3.4e38f;
  float c0 = 3.4e38f, c1 = 3.4e38f, c2 = 3.4e38f;
  int ia0 = 0, ia1 = 0, ia2 = 0, ic0 = 0, ic1 = 0, ic2 = 0;
#pragma unroll 8
  for (int t = 0; t < 64; ++t) {
    const int sw = ll ^ (t & 7);
    const float4 pA = cposI[t * 8 + sw];
    const float4 pB = cposI[(t + 64) * 8 + sw];
    const float dxA = __fsub_rn(fx, pA.x), dyA = __fsub_rn(fy, pA.y),
                dzA = __fsub_rn(fz, pA.z);
    const float dxB = __fsub_rn(fx, pB.x), dyB = __fsub_rn(fy, pB.y),
                dzB = __fsub_rn(fz, pB.z);
    const float d2A = __fadd_rn(
        __fadd_rn(__fmul_rn(dxA, dxA), __fmul_rn(dyA, dyA)),
        __fmul_rn(dzA, dzA));
    const float d2B = __fadd_rn(
        __fadd_rn(__fmul_rn(dxB, dxB), __fmul_rn(dyB, dyB)),
        __fmul_rn(dzB, dzB));
    ins3(d2A, jb + t,      a0, a1, a2, ia0, ia1, ia2);
    ins3(d2B, jb + 64 + t, c0, c1, c2, ic0, ic1, ic2);
  }
  // merge chain B into A (B indices all larger -> strict-< correct)
  ins3(c0, ic0, a0, a1, a2, ia0, ia1, ia2);
  ins3(c1, ic1, a0, a1, a2, ia0, ia1, ia2);
  ins3(c2, ic2, a0, a1, a2, ia0, ia1, ia2);

  // symmetric butterfly across the 8-lane group -> all lanes converge
#pragma unroll
  for (int mm = 1; mm <= 4; mm <<= 1) {
    const float o0 = __shfl_xor(a0, mm);
    const float o1 = __shfl_xor(a1, mm);
    const float o2 = __shfl_xor(a2, mm);
    const int oj0 = __shfl_xor(ia0, mm);
    const int oj1 = __shfl_xor(ia1, mm);
    const int oj2 = __shfl_xor(ia2, mm);
    ins3tb(o0, oj0, a0, a1, a2, ia0, ia1, ia2);
    ins3tb(o1, oj1, a0, a1, a2, ia0, ia1, ia2);
    ins3tb(o2, oj2, a0, a1, a2, ia0, ia1, ia2);
  }

  // weights (every lane of the group computes its point's weights)
  float w0 = 1.f / fmaxf(a0, 1e-16f);
  float w1 = 1.f / fmaxf(a1, 1e-16f);
  float w2 = 1.f / fmaxf(a2, 1e-16f);
  const float inv = 1.f / (w0 + w1 + w2);
  w0 *= inv; w1 *= inv; w2 *= inv;

  // gather: 8 lanes split the point's 256 cols; f = k*8+ll keeps each
  // group's loads/stores contiguous (128B / 64B segments).
  const float4* r0 = (const float4*)(x + (size_t)(b * NC + ia0) * CIN);
  const float4* r1 = (const float4*)(x + (size_t)(b * NC + ia1) * CIN);
  const float4* r2 = (const float4*)(x + (size_t)(b * NC + ia2) * CIN);
  __hip_bfloat16* orow = h0 + (size_t)f * DIN;
  unsigned int* o2u = (unsigned int*)orow;
#pragma unroll
  for (int k = 0; k < 8; ++k) {
    const int fi4 = k * 8 + ll;
    const float4 A = r0[fi4], B = r1[fi4], C = r2[fi4];
    float4 v;
    v.x = w0 * A.x + w1 * B.x + w2 * C.x;
    v.y = w0 * A.y + w1 * B.y + w2 * C.y;
    v.z = w0 * A.z + w1 * B.z + w2 * C.z;
    v.w = w0 * A.w + w1 * B.w + w2 * C.w;
    uint2 o;
    o.x = pack2(v.x, v.y);
    o.y = pack2(v.z, v.w);
    ((uint2*)o2u)[fi4] = o;
  }
  // skip copy: 128 f32 -> bf16 (4 float4s per lane)
  const float4* xs = (const float4*)(x_skip + (size_t)f * CSK);
  unsigned int* o2s = (unsigned int*)(orow + CIN);
#pragma unroll
  for (int k = 0; k < 4; ++k) {
    const int fi4 = k * 8 + ll;
    const float4 s = xs[fi4];
    uint2 o;
    o.x = pack2(s.x, s.y);
    o.y = pack2(s.z, s.w);
    ((uint2*)o2s)[fi4] = o;
  }
}

// ---------------------------------------------------------------------------
// Fused BN1-finalize + W2 fold + b2 fold.
// ---------------------------------------------------------------------------
__global__ __launch_bounds__(256) void prep_w2b2_kernel(
    const float* __restrict__ W2, const float* __restrict__ stats,
    const float* __restrict__ g1, const float* __restrict__ be1,
    const float* __restrict__ b2, __hip_bfloat16* __restrict__ W2t,
    float* __restrict__ b2p) {
  const int n = blockIdx.x, c = threadIdx.x;
  const int wid = c >> 6, lane = c & 63;
  const float m = stats[c] * (1.f / MROWS);
  const float var = stats[256 + c] * (1.f / MROWS) - m * m;
  const float sc = g1[c] * rsqrtf(var + BN_EPS);
  const float sh = be1[c] - m * sc;
  const float w = W2[(size_t)c * CHID + n];
  W2t[(size_t)n * CHID + c] = __float2bfloat16(sc * w);
  float p = sh * w;
#pragma unroll
  for (int off = 32; off > 0; off >>= 1) p += __shfl_down(p, off);
  __shared__ float red4[4];
  if (lane == 0) red4[wid] = p;
  __syncthreads();
  if (c == 0) b2p[n] = red4[0] + red4[1] + red4[2] + red4[3] + b2[n];
}

// ---------------------------------------------------------------------------
// GEMM: Z(M x 256) = relu(A(M x KD) @ Bt^T + bias), bf16 out, fused
// per-column sum/sumsq for BN. 128x256 tile, BK=32, 8 waves (2x4 of 64x64),
// 2-phase prefetch double-buffered LDS (proven r6 structure).
// ---------------------------------------------------------------------------
template<int KD>
__global__ __launch_bounds__(512) void gemm_bias_relu(
    const __hip_bfloat16* __restrict__ A,   // M x KD
    const __hip_bfloat16* __restrict__ Bt,  // 256 x KD
    const float* __restrict__ bias,         // 256
    __hip_bfloat16* __restrict__ out,       // M x 256 (bf16)
    float* __restrict__ gsum,               // 256
    float* __restrict__ gsq)                // 256
{
  __shared__ __hip_bfloat16 As[2 * 128 * 32];   // 16 KB
  __shared__ __hip_bfloat16 Bs[2 * 256 * 32];   // 32 KB
  __shared__ float ssum[256], ssq[256];
  const int tid = threadIdx.x;
  const int wid = tid >> 6, lane = tid & 63;
  const int bm = blockIdx.x;
  const int wr = wid >> 2, wc = wid & 3;
  const int la = lane & 15, lk = lane >> 4;

  if (tid < 256) { ssum[tid] = 0.f; ssq[tid] = 0.f; }

  f32x4 acc[4][4] = {};

  const int rA = tid >> 2;
  const int c8 = (tid & 3) * 8;
  const __hip_bfloat16* gA  = A  + (size_t)(bm * 128 + rA) * KD + c8;
  const __hip_bfloat16* gB0 = Bt + (size_t)rA * KD + c8;
  const __hip_bfloat16* gB1 = Bt + (size_t)(128 + rA) * KD + c8;
  char* ldsA  = (char*)As + wid * 1024;
  char* ldsB0 = (char*)Bs + wid * 1024;

  load_lds16(gA,  ldsA);
  load_lds16(gB0, ldsB0);
  load_lds16(gB1, ldsB0 + 8192);
  __syncthreads();

  const int nIter = KD / 32;
  for (int it = 0; it < nIter; ++it) {
    const int cur = it & 1, nxt = cur ^ 1;
    if (it + 1 < nIter) {
      const int k1 = (it + 1) * 32;
      load_lds16(gA  + k1, ldsA  + nxt * 8192);
      load_lds16(gB0 + k1, ldsB0 + nxt * 16384);
      load_lds16(gB1 + k1, ldsB0 + nxt * 16384 + 8192);
    }
    const __hip_bfloat16* Acur = As + cur * 4096;
    const __hip_bfloat16* Bcur = Bs + cur * 8192;
    bf16x8 af[4], bfr[4];
#pragma unroll
    for (int m = 0; m < 4; ++m)
      af[m] = *(const bf16x8*)(Acur + (wr * 64 + m * 16 + la) * 32 + lk * 8);
#pragma unroll
    for (int n = 0; n < 4; ++n)
      bfr[n] = *(const bf16x8*)(Bcur + (wc * 64 + n * 16 + la) * 32 + lk * 8);
#pragma unroll
    for (int m = 0; m < 4; ++m)
#pragma unroll
      for (int n = 0; n < 4; ++n)
        acc[m][n] = __builtin_amdgcn_mfma_f32_16x16x32_bf16(
            af[m], bfr[n], acc[m][n], 0, 0, 0);
    __syncthreads();
  }

  const int rowBase = bm * 128 + wr * 64 + lk * 4;
#pragma unroll
  for (int n = 0; n < 4; ++n) {
    const int col = wc * 64 + n * 16 + la;
    const float bs = bias[col];
    float ls = 0.f, ls2 = 0.f;
#pragma unroll
    for (int m = 0; m < 4; ++m) {
      const int row = rowBase + m * 16;
#pragma unroll
      for (int j = 0; j < 4; ++j) {
        float v = acc[m][n][j] + bs;
        v = fmaxf(v, 0.f);
        ls += v; ls2 += v * v;
        out[(size_t)(row + j) * 256 + col] = __float2bfloat16(v);
      }
    }
    atomicAdd(&ssum[col], ls);
    atomicAdd(&ssq[col], ls2);
  }
  __syncthreads();
  if (tid < 256) {
    atomicAdd(&gsum[tid], ssum[tid]);
    atomicAdd(&gsq[tid], ssq[tid]);
  }
}

// ---------------------------------------------------------------------------
// bn apply (with inlined BN2 finalize): read bf16 z2, write f32 out.
// ---------------------------------------------------------------------------
__global__ __launch_bounds__(256) void bn_apply_kernel(
    const __hip_bfloat16* __restrict__ Z, const float* __restrict__ stats,
    const float* __restrict__ g2, const float* __restrict__ be2,
    float* __restrict__ out) {
  __shared__ float ssc[256], ssh[256];
  const int t = threadIdx.x;
  {
    const float m = stats[t] * (1.f / MROWS);
    const float var = stats[256 + t] * (1.f / MROWS) - m * m;
    const float sc = g2[t] * rsqrtf(var + BN_EPS);
    ssc[t] = sc;
    ssh[t] = be2[t] - m * sc;
  }
  __syncthreads();
  const size_t i8 = (size_t)blockIdx.x * 256 + t;  // 8-elem index
  const uint4 raw = ((const uint4*)Z)[i8];
  const int c0 = (int)((i8 * 8) & 255);
  const float4 scA = *(const float4*)(ssc + c0);
  const float4 scB = *(const float4*)(ssc + c0 + 4);
  const float4 shA = *(const float4*)(ssh + c0);
  const float4 shB = *(const float4*)(ssh + c0 + 4);
  float4 oa, ob;
  oa.x = bfu2f((unsigned short)(raw.x & 0xffff)) * scA.x + shA.x;
  oa.y = bfu2f((unsigned short)(raw.x >> 16))    * scA.y + shA.y;
  oa.z = bfu2f((unsigned short)(raw.y & 0xffff)) * scA.z + shA.z;
  oa.w = bfu2f((unsigned short)(raw.y >> 16))    * scA.w + shA.w;
  ob.x = bfu2f((unsigned short)(raw.z & 0xffff)) * scB.x + shB.x;
  ob.y = bfu2f((unsigned short)(raw.z >> 16))    * scB.y + shB.y;
  ob.z = bfu2f((unsigned short)(raw.w & 0xffff)) * scB.z + shB.z;
  ob.w = bfu2f((unsigned short)(raw.w >> 16))    * scB.w + shB.w;
  ((float4*)(out))[i8 * 2]     = oa;
  ((float4*)(out))[i8 * 2 + 1] = ob;
}

// ---------------------------------------------------------------------------
extern "C" void kernel_launch(void* const* d_in, const int* in_sizes, int n_in,
                              void* d_out, int out_size, void* d_ws,
                              size_t ws_size, hipStream_t stream) {
  (void)in_sizes; (void)n_in; (void)out_size; (void)ws_size;
  const float* x        = (const float*)d_in[0];
  const float* pos      = (const float*)d_in[1];
  const float* x_skip   = (const float*)d_in[3];
  const float* pos_skip = (const float*)d_in[4];
  const float* W1  = (const float*)d_in[6];
  const float* b1  = (const float*)d_in[7];
  const float* g1  = (const float*)d_in[8];
  const float* be1 = (const float*)d_in[9];
  const float* W2  = (const float*)d_in[10];
  const float* b2  = (const float*)d_in[11];
  const float* g2  = (const float*)d_in[12];
  const float* be2 = (const float*)d_in[13];
  float* out = (float*)d_out;

  char* ws = (char*)d_ws;
  // Workspace layout (bytes); z2 aliases h0 (h0 dead after gemm1)
  __hip_bfloat16* h0  = (__hip_bfloat16*)(ws);                    // 50331648
  __hip_bfloat16* z2  = (__hip_bfloat16*)(ws);                    // 33554432
  __hip_bfloat16* W1t = (__hip_bfloat16*)(ws + 50331648);         // 196608
  __hip_bfloat16* z1  = (__hip_bfloat16*)(ws + 50528256);         // 33554432
  __hip_bfloat16* W2t = (__hip_bfloat16*)(ws + 84082688);         // 131072
  float* b2p    = (float*)(ws + 84213760);                        // 1024
  float* stats  = (float*)(ws + 84214784);                        // 4096

  knn_interp_kernel<<<2432, 256, 0, stream>>>(x, pos, x_skip, pos_skip, h0,
                                              W1, W1t, stats);
  gemm_bias_relu<DIN><<<512, 512, 0, stream>>>(h0, W1t, b1, z1,
                                               stats, stats + 256);
  prep_w2b2_kernel<<<256, 256, 0, stream>>>(W2, stats, g1, be1, b2, W2t, b2p);
  gemm_bias_relu<CHID><<<512, 512, 0, stream>>>(z1, W2t, b2p, z2,
                                                stats + 512, stats + 768);
  bn_apply_kernel<<<8192, 256, 0, stream>>>(z2, stats + 512, g2, be2, out);
}